// Round 1
// baseline (506.447 us; speedup 1.0000x reference)
//
#include <hip/hip_runtime.h>
#include <hip/hip_bf16.h>

typedef __bf16 bf16;
typedef __attribute__((ext_vector_type(8))) __bf16 bf16x8;
typedef __attribute__((ext_vector_type(4))) __bf16 bf16x4;
typedef __attribute__((ext_vector_type(4))) float  f32x4;

typedef const void __attribute__((address_space(1)))* gas_t;
typedef void __attribute__((address_space(3)))* las_t;

__device__ __forceinline__ void gload16(const void* g, void* l) {
  __builtin_amdgcn_global_load_lds((gas_t)g, (las_t)l, 16, 0, 0);
}
__device__ __forceinline__ f32x4 mfma16(bf16x8 a, bf16x8 b, f32x4 c) {
  return __builtin_amdgcn_mfma_f32_16x16x32_bf16(a, b, c, 0, 0, 0);
}

constexpr int SEQL = 2048;
constexpr int DM   = 2048;   // model dim
constexpr int HD   = 128;    // head dim
constexpr int MR   = 4096;   // B*S rows

// ---------------- fp32 -> bf16 convert (x) ----------------
__global__ __launch_bounds__(256) void cvt_x(const float* __restrict__ x,
                                             bf16* __restrict__ xb) {
  const size_t i = ((size_t)blockIdx.x * 256 + threadIdx.x) * 4;
  const f32x4 v = *reinterpret_cast<const f32x4*>(x + i);
  bf16x4 o;
  #pragma unroll
  for (int j = 0; j < 4; ++j) o[j] = (bf16)v[j];
  *reinterpret_cast<bf16x4*>(xb + i) = o;
}

// ---------------- weight transpose + convert: [K][N] f32 -> [N][K] bf16 ----------------
__global__ __launch_bounds__(256) void transpose_w(
    const float* __restrict__ w0, const float* __restrict__ w1,
    const float* __restrict__ w2, const float* __restrict__ w3,
    bf16* __restrict__ wqkvt, bf16* __restrict__ wot) {
  const int z = blockIdx.z;
  const float* src = (z == 0) ? w0 : (z == 1) ? w1 : (z == 2) ? w2 : w3;
  bf16* dst = (z < 3) ? (wqkvt + (size_t)z * DM * DM) : wot;
  __shared__ float tile[32][33];
  const int tx = threadIdx.x, ty = threadIdx.y;
  const int x0 = blockIdx.x * 32, y0 = blockIdx.y * 32;
  #pragma unroll
  for (int i = 0; i < 4; ++i)
    tile[ty + 8 * i][tx] = src[(size_t)(y0 + ty + 8 * i) * DM + x0 + tx];
  __syncthreads();
  #pragma unroll
  for (int i = 0; i < 4; ++i)
    dst[(size_t)(x0 + ty + 8 * i) * DM + y0 + tx] = (bf16)tile[tx][ty + 8 * i];
}

// ---------------- RoPE (in-place on Q and K, bf16) ----------------
__global__ __launch_bounds__(256) void rope_k(bf16* __restrict__ Q,
                                              bf16* __restrict__ Kk,
                                              const float* __restrict__ fc,
                                              const float* __restrict__ fs) {
  bf16* X = blockIdx.y ? Kk : Q;
  const size_t tid = (size_t)blockIdx.x * 256 + threadIdx.x;
  const size_t e0 = tid * 8;                 // 8 bf16 = 4 rot pairs
  const int col = (int)(e0 & (DM - 1));
  const int row = (int)(e0 >> 11);
  const int s   = row & (SEQL - 1);
  const int p0  = (col & (HD - 1)) >> 1;     // pair index, multiple of 4
  bf16x8 v = *reinterpret_cast<bf16x8*>(X + e0);
  const f32x4 c  = *reinterpret_cast<const f32x4*>(fc + (size_t)s * 64 + p0);
  const f32x4 sn = *reinterpret_cast<const f32x4*>(fs + (size_t)s * 64 + p0);
  #pragma unroll
  for (int j = 0; j < 4; ++j) {
    const float x0 = (float)v[2 * j], x1 = (float)v[2 * j + 1];
    v[2 * j]     = (bf16)(x0 * c[j] - x1 * sn[j]);
    v[2 * j + 1] = (bf16)(x0 * sn[j] + x1 * c[j]);
  }
  *reinterpret_cast<bf16x8*>(X + e0) = v;
}

// ---------------- m97-style bf16 GEMM: C[M][N] = A[M][K] * Bt[N][K]^T ----------------
// 128x128 tile, BK=32, 4 waves (each 64x64), global_load_lds staging with
// 4-slot XOR swizzle (key row&3) applied via pre-swizzled global source.
template <bool MULTI, bool OUTF32>
__global__ __launch_bounds__(256) void gemm_bt(
    const bf16* __restrict__ A, const bf16* __restrict__ Bt,
    bf16* __restrict__ Cb, float* __restrict__ Cf,
    const int M, const int N, const int K) {
  const int t = threadIdx.x;
  const int wid = t >> 6, lane = t & 63, lo = lane & 15, hi = lane >> 4;
  const int m0 = blockIdx.y * 128, n0 = blockIdx.x * 128;
  const bf16* Bt_ = Bt;
  bf16* Cb_ = Cb;
  if (MULTI) {
    const size_t z = blockIdx.z;
    Bt_ += z * (size_t)N * K;
    Cb_ += z * (size_t)M * N;
  }
  __shared__ bf16 As[128 * 32];
  __shared__ bf16 Bs[128 * 32];
  const int wr = wid >> 1, wc = wid & 1;
  const f32x4 zero4 = {0.f, 0.f, 0.f, 0.f};
  f32x4 acc[4][4];
  #pragma unroll
  for (int i = 0; i < 4; ++i)
    #pragma unroll
    for (int j = 0; j < 4; ++j) acc[i][j] = zero4;

  const int r_a = t >> 2;                       // staged row (per 64-row issue)
  const int ul  = ((t & 3) ^ (r_a & 3)) * 8;    // pre-swizzled k-unit offset
  const bf16* gA0 = A   + (size_t)(m0 + r_a) * K + ul;
  const bf16* gB0 = Bt_ + (size_t)(n0 + r_a) * K + ul;
  char* lA = (char*)As + wid * 1024;
  char* lB = (char*)Bs + wid * 1024;

  const int ru = (hi ^ (lo & 3)) * 8;           // read-side swizzled unit

  for (int k0 = 0; k0 < K; k0 += 32) {
    gload16(gA0 + k0, lA);
    gload16(gA0 + (size_t)64 * K + k0, lA + 4096);
    gload16(gB0 + k0, lB);
    gload16(gB0 + (size_t)64 * K + k0, lB + 4096);
    __syncthreads();
    bf16x8 af[4], bb[4];
    #pragma unroll
    for (int i = 0; i < 4; ++i)
      af[i] = *reinterpret_cast<const bf16x8*>(As + (wr * 64 + i * 16 + lo) * 32 + ru);
    #pragma unroll
    for (int i = 0; i < 4; ++i)
      bb[i] = *reinterpret_cast<const bf16x8*>(Bs + (wc * 64 + i * 16 + lo) * 32 + ru);
    #pragma unroll
    for (int mi = 0; mi < 4; ++mi)
      #pragma unroll
      for (int ni = 0; ni < 4; ++ni)
        acc[mi][ni] = mfma16(af[mi], bb[ni], acc[mi][ni]);
    __syncthreads();
  }
  // epilogue: C/D layout col=lane&15, row=(lane>>4)*4+r   [verified m89/m91]
  #pragma unroll
  for (int mi = 0; mi < 4; ++mi)
    #pragma unroll
    for (int ni = 0; ni < 4; ++ni)
      #pragma unroll
      for (int r = 0; r < 4; ++r) {
        const size_t row = m0 + wr * 64 + mi * 16 + hi * 4 + r;
        const size_t col = n0 + wc * 64 + ni * 16 + lo;
        if (OUTF32) Cf[row * N + col] = acc[mi][ni][r];
        else        Cb_[row * N + col] = (bf16)acc[mi][ni][r];
      }
}

// ---------------- causal flash attention fwd ----------------
// block = 256 thr (4 waves), 64 q-rows/block (16/wave), KVBLK=64.
// K staged via global_load_lds with pre-swizzled source (key row&15);
// V staged transposed+swizzled (key (d^(d>>3))&7); P via per-wave swizzled LDS.
__global__ __launch_bounds__(256) void flash_fwd(
    const bf16* __restrict__ Qg, const bf16* __restrict__ Kg,
    const bf16* __restrict__ Vg, bf16* __restrict__ Og) {
  const int t = threadIdx.x;
  const int wid = t >> 6, lane = t & 63, lo = lane & 15, hi = lane >> 4;
  const int q0 = blockIdx.x * 64;
  const int h  = blockIdx.y;
  const int b  = blockIdx.z;

  __shared__ bf16 Ks[64 * 128];    // [kv][d]  swizzled (16 units/row, key kv&15)
  __shared__ bf16 Vt[128 * 64];    // [d][kv]  swizzled (8 units/row, key (d^(d>>3))&7)
  __shared__ bf16 Ps[4][16 * 64];  // per-wave P [qrow][kv] swizzled (key row&7)

  const size_t hoff = (size_t)b * SEQL * DM + (size_t)h * HD;

  // Q A-frags in registers: row = lo, k chunk = kc*32 + hi*8
  bf16x8 qf[4];
  {
    const bf16* qrow = Qg + hoff + (size_t)(q0 + wid * 16 + lo) * DM;
    #pragma unroll
    for (int kc = 0; kc < 4; ++kc)
      qf[kc] = *reinterpret_cast<const bf16x8*>(qrow + kc * 32 + hi * 8);
  }

  const f32x4 zero4 = {0.f, 0.f, 0.f, 0.f};
  f32x4 acc[8];
  #pragma unroll
  for (int i = 0; i < 8; ++i) acc[i] = zero4;
  float m_r[4], l_r[4];
  #pragma unroll
  for (int r = 0; r < 4; ++r) { m_r[r] = -1e30f; l_r[r] = 0.f; }

  const int ntiles = q0 / 64 + 1;
  const float scale = 0.08838834764831845f;   // 1/sqrt(128)

  const int krow = t >> 4;                    // 0..15 (K staging row-within-issue)
  const int kul  = ((t & 15) ^ krow) * 8;     // pre-swizzled k-unit
  const int vd0  = (t & 31) * 4;              // V staging: 4 d-columns per thread
  const int vg   = t >> 5;                    // kv-group 0..7

  for (int it = 0; it < ntiles; ++it) {
    const int kv0 = it * 64;
    // ---- stage K tile (4 x global_load_lds, pre-swizzled source) ----
    {
      const bf16* gK = Kg + hoff + (size_t)(kv0 + krow) * DM + kul;
      char* lK = (char*)Ks + wid * 1024;
      #pragma unroll
      for (int j = 0; j < 4; ++j)
        gload16(gK + (size_t)j * 16 * DM, lK + j * 4096);
    }
    // ---- stage V^T tile (coalesced 8B loads -> swizzled ds_write_b128) ----
    {
      const bf16* gV = Vg + hoff + (size_t)kv0 * DM + vd0;
      bf16x4 ld[8];
      #pragma unroll
      for (int e = 0; e < 8; ++e)
        ld[e] = *reinterpret_cast<const bf16x4*>(gV + (size_t)(vg * 8 + e) * DM);
      #pragma unroll
      for (int c = 0; c < 4; ++c) {
        const int d = vd0 + c;
        const int sw = (d ^ (d >> 3)) & 7;
        bf16x8 pk;
        #pragma unroll
        for (int e = 0; e < 8; ++e) pk[e] = ld[e][c];
        *reinterpret_cast<bf16x8*>(Vt + d * 64 + ((vg ^ sw) * 8)) = pk;
      }
    }
    __syncthreads();

    // ---- S = Q K^T (per wave 16x64) ----
    f32x4 s[4];
    #pragma unroll
    for (int nf = 0; nf < 4; ++nf) s[nf] = zero4;
    #pragma unroll
    for (int nf = 0; nf < 4; ++nf) {
      const bf16* krp = Ks + (nf * 16 + lo) * 128;
      #pragma unroll
      for (int kc = 0; kc < 4; ++kc) {
        const bf16x8 kb = *reinterpret_cast<const bf16x8*>(krp + (((kc * 4 + hi) ^ lo) * 8));
        s[nf] = mfma16(qf[kc], kb, s[nf]);
      }
    }
    // ---- scale + causal mask (only boundary tile kv0==q0 needs masking) ----
    const bool boundary = (kv0 == q0);
    #pragma unroll
    for (int nf = 0; nf < 4; ++nf)
      #pragma unroll
      for (int r = 0; r < 4; ++r) {
        float v = s[nf][r] * scale;
        if (boundary && (nf * 16 + lo > wid * 16 + hi * 4 + r)) v = -1e30f;
        s[nf][r] = v;
      }
    // ---- online softmax ----
    float fctr[4];
    #pragma unroll
    for (int r = 0; r < 4; ++r) {
      float mx = fmaxf(fmaxf(s[0][r], s[1][r]), fmaxf(s[2][r], s[3][r]));
      #pragma unroll
      for (int msk = 1; msk < 16; msk <<= 1) mx = fmaxf(mx, __shfl_xor(mx, msk, 64));
      const float mnew = fmaxf(m_r[r], mx);
      fctr[r] = __expf(m_r[r] - mnew);
      m_r[r] = mnew;
      float sum = 0.f;
      #pragma unroll
      for (int nf = 0; nf < 4; ++nf) {
        const float p = __expf(s[nf][r] - mnew);
        s[nf][r] = p;
        sum += p;
      }
      l_r[r] = l_r[r] * fctr[r] + sum;
    }
    #pragma unroll
    for (int i = 0; i < 8; ++i)
      #pragma unroll
      for (int r = 0; r < 4; ++r) acc[i][r] *= fctr[r];
    // ---- P -> per-wave LDS (bf16, swizzled key row&7) ----
    bf16* myP = Ps[wid];
    #pragma unroll
    for (int nf = 0; nf < 4; ++nf)
      #pragma unroll
      for (int r = 0; r < 4; ++r) {
        const int row = hi * 4 + r;
        const int col = nf * 16 + lo;
        myP[row * 64 + (((col >> 3) ^ (row & 7)) * 8) + (col & 7)] = (bf16)s[nf][r];
      }
    // ---- P A-frags (same-wave RAW; compiler inserts lgkmcnt) ----
    bf16x8 pa[2];
    #pragma unroll
    for (int kc = 0; kc < 2; ++kc)
      pa[kc] = *reinterpret_cast<const bf16x8*>(myP + lo * 64 + (((kc * 4 + hi) ^ (lo & 7)) * 8));
    // ---- O += P V ----
    #pragma unroll
    for (int nf = 0; nf < 8; ++nf) {
      const int d = nf * 16 + lo;
      const int sw = (d ^ (d >> 3)) & 7;
      const bf16* vrp = Vt + d * 64;
      #pragma unroll
      for (int kc = 0; kc < 2; ++kc) {
        const bf16x8 bv = *reinterpret_cast<const bf16x8*>(vrp + (((kc * 4 + hi) ^ sw) * 8));
        acc[nf] = mfma16(pa[kc], bv, acc[nf]);
      }
    }
    __syncthreads();
  }

  // ---- finalize: row-sum reduce + normalize + store ----
  #pragma unroll
  for (int r = 0; r < 4; ++r) {
    float l = l_r[r];
    #pragma unroll
    for (int msk = 1; msk < 16; msk <<= 1) l += __shfl_xor(l, msk, 64);
    l_r[r] = 1.f / l;
  }
  #pragma unroll
  for (int nf = 0; nf < 8; ++nf)
    #pragma unroll
    for (int r = 0; r < 4; ++r) {
      const size_t row = q0 + wid * 16 + hi * 4 + r;
      Og[hoff + row * DM + nf * 16 + lo] = (bf16)(acc[nf][r] * l_r[r]);
    }
}

extern "C" void kernel_launch(void* const* d_in, const int* in_sizes, int n_in,
                              void* d_out, int out_size, void* d_ws, size_t ws_size,
                              hipStream_t stream) {
  const float* x  = (const float*)d_in[0];
  const float* wq = (const float*)d_in[1];
  const float* wk = (const float*)d_in[2];
  const float* wv = (const float*)d_in[3];
  const float* wo = (const float*)d_in[4];
  const float* fc = (const float*)d_in[5];
  const float* fs = (const float*)d_in[6];
  float* out = (float*)d_out;

  // workspace layout (96 MB total)
  char* ws = (char*)d_ws;
  bf16* xb    = (bf16*)ws;                      // 16MB  x bf16 [4096][2048]; reused as O
  bf16* wqkvt = (bf16*)(ws + (16ull << 20));    // 24MB  [3][2048 n][2048 k]
  bf16* wot   = (bf16*)(ws + (40ull << 20));    //  8MB  [2048 n][2048 k]
  bf16* qkv   = (bf16*)(ws + (48ull << 20));    // 48MB  [3][4096][2048]
  bf16* Qb = qkv;
  bf16* Kb = qkv + (size_t)MR * DM;
  bf16* Vb = qkv + 2 * (size_t)MR * DM;

  cvt_x<<<8192, 256, 0, stream>>>(x, xb);
  transpose_w<<<dim3(64, 64, 4), dim3(32, 8), 0, stream>>>(wq, wk, wv, wo, wqkvt, wot);
  gemm_bt<true, false><<<dim3(16, 32, 3), 256, 0, stream>>>(xb, wqkvt, qkv, nullptr, MR, DM, DM);
  rope_k<<<dim3(4096, 2), 256, 0, stream>>>(Qb, Kb, fc, fs);
  flash_fwd<<<dim3(32, 16, 2), 256, 0, stream>>>(Qb, Kb, Vb, xb /*O*/);
  gemm_bt<false, true><<<dim3(16, 32), 256, 0, stream>>>(xb, wot, nullptr, out, MR, DM, DM);
}

// Round 3
// 437.861 us; speedup vs baseline: 1.1566x; 1.1566x over previous
//
#include <hip/hip_runtime.h>
#include <hip/hip_bf16.h>

typedef __bf16 bf16;
typedef __attribute__((ext_vector_type(8))) __bf16 bf16x8;
typedef __attribute__((ext_vector_type(4))) __bf16 bf16x4;
typedef __attribute__((ext_vector_type(4))) float  f32x4;

typedef const void __attribute__((address_space(1)))* gas_t;
typedef void __attribute__((address_space(3)))* las_t;

__device__ __forceinline__ void gload16(const void* g, void* l) {
  __builtin_amdgcn_global_load_lds((gas_t)g, (las_t)l, 16, 0, 0);
}
__device__ __forceinline__ f32x4 mfma16(bf16x8 a, bf16x8 b, f32x4 c) {
  return __builtin_amdgcn_mfma_f32_16x16x32_bf16(a, b, c, 0, 0, 0);
}

constexpr int SEQL = 2048;
constexpr int DM   = 2048;   // model dim
constexpr int HD   = 128;    // head dim
constexpr int MR   = 4096;   // B*S rows

// ---------------- fp32 -> bf16 convert (x) ----------------
__global__ __launch_bounds__(256) void cvt_x(const float* __restrict__ x,
                                             bf16* __restrict__ xb) {
  const size_t i = ((size_t)blockIdx.x * 256 + threadIdx.x) * 4;
  const f32x4 v = *reinterpret_cast<const f32x4*>(x + i);
  bf16x4 o;
  #pragma unroll
  for (int j = 0; j < 4; ++j) o[j] = (bf16)v[j];
  *reinterpret_cast<bf16x4*>(xb + i) = o;
}

// ---------------- weight transpose + convert: [K][N] f32 -> [N][K] bf16 ----------------
__global__ __launch_bounds__(256) void transpose_w(
    const float* __restrict__ w0, const float* __restrict__ w1,
    const float* __restrict__ w2, const float* __restrict__ w3,
    bf16* __restrict__ wqkvt, bf16* __restrict__ wot) {
  const int z = blockIdx.z;
  const float* src = (z == 0) ? w0 : (z == 1) ? w1 : (z == 2) ? w2 : w3;
  bf16* dst = (z < 3) ? (wqkvt + (size_t)z * DM * DM) : wot;
  __shared__ float tile[32][33];
  const int tx = threadIdx.x, ty = threadIdx.y;
  const int x0 = blockIdx.x * 32, y0 = blockIdx.y * 32;
  #pragma unroll
  for (int i = 0; i < 4; ++i)
    tile[ty + 8 * i][tx] = src[(size_t)(y0 + ty + 8 * i) * DM + x0 + tx];
  __syncthreads();
  #pragma unroll
  for (int i = 0; i < 4; ++i)
    dst[(size_t)(x0 + ty + 8 * i) * DM + y0 + tx] = (bf16)tile[tx][ty + 8 * i];
}

// ---------------- RoPE (in-place on Q and K, bf16) ----------------
__global__ __launch_bounds__(256) void rope_k(bf16* __restrict__ Q,
                                              bf16* __restrict__ Kk,
                                              const float* __restrict__ fc,
                                              const float* __restrict__ fs) {
  bf16* X = blockIdx.y ? Kk : Q;
  const size_t tid = (size_t)blockIdx.x * 256 + threadIdx.x;
  const size_t e0 = tid * 8;                 // 8 bf16 = 4 rot pairs
  const int col = (int)(e0 & (DM - 1));
  const int row = (int)(e0 >> 11);
  const int s   = row & (SEQL - 1);
  const int p0  = (col & (HD - 1)) >> 1;     // pair index, multiple of 4
  bf16x8 v = *reinterpret_cast<bf16x8*>(X + e0);
  const f32x4 c  = *reinterpret_cast<const f32x4*>(fc + (size_t)s * 64 + p0);
  const f32x4 sn = *reinterpret_cast<const f32x4*>(fs + (size_t)s * 64 + p0);
  #pragma unroll
  for (int j = 0; j < 4; ++j) {
    const float x0 = (float)v[2 * j], x1 = (float)v[2 * j + 1];
    v[2 * j]     = (bf16)(x0 * c[j] - x1 * sn[j]);
    v[2 * j + 1] = (bf16)(x0 * sn[j] + x1 * c[j]);
  }
  *reinterpret_cast<bf16x8*>(X + e0) = v;
}

// ---------------- m97-style bf16 GEMM: C[M][N] = A[M][K] * Bt[N][K]^T ----------------
template <bool MULTI, bool OUTF32>
__global__ __launch_bounds__(256) void gemm_bt(
    const bf16* __restrict__ A, const bf16* __restrict__ Bt,
    bf16* __restrict__ Cb, float* __restrict__ Cf,
    const int M, const int N, const int K) {
  const int t = threadIdx.x;
  const int wid = t >> 6, lane = t & 63, lo = lane & 15, hi = lane >> 4;
  const int m0 = blockIdx.y * 128, n0 = blockIdx.x * 128;
  const bf16* Bt_ = Bt;
  bf16* Cb_ = Cb;
  if (MULTI) {
    const size_t z = blockIdx.z;
    Bt_ += z * (size_t)N * K;
    Cb_ += z * (size_t)M * N;
  }
  __shared__ bf16 As[128 * 32];
  __shared__ bf16 Bs[128 * 32];
  const int wr = wid >> 1, wc = wid & 1;
  const f32x4 zero4 = {0.f, 0.f, 0.f, 0.f};
  f32x4 acc[4][4];
  #pragma unroll
  for (int i = 0; i < 4; ++i)
    #pragma unroll
    for (int j = 0; j < 4; ++j) acc[i][j] = zero4;

  const int r_a = t >> 2;
  const int ul  = ((t & 3) ^ (r_a & 3)) * 8;
  const bf16* gA0 = A   + (size_t)(m0 + r_a) * K + ul;
  const bf16* gB0 = Bt_ + (size_t)(n0 + r_a) * K + ul;
  char* lA = (char*)As + wid * 1024;
  char* lB = (char*)Bs + wid * 1024;

  const int ru = (hi ^ (lo & 3)) * 8;

  for (int k0 = 0; k0 < K; k0 += 32) {
    gload16(gA0 + k0, lA);
    gload16(gA0 + (size_t)64 * K + k0, lA + 4096);
    gload16(gB0 + k0, lB);
    gload16(gB0 + (size_t)64 * K + k0, lB + 4096);
    __syncthreads();
    bf16x8 af[4], bb[4];
    #pragma unroll
    for (int i = 0; i < 4; ++i)
      af[i] = *reinterpret_cast<const bf16x8*>(As + (wr * 64 + i * 16 + lo) * 32 + ru);
    #pragma unroll
    for (int i = 0; i < 4; ++i)
      bb[i] = *reinterpret_cast<const bf16x8*>(Bs + (wc * 64 + i * 16 + lo) * 32 + ru);
    #pragma unroll
    for (int mi = 0; mi < 4; ++mi)
      #pragma unroll
      for (int ni = 0; ni < 4; ++ni)
        acc[mi][ni] = mfma16(af[mi], bb[ni], acc[mi][ni]);
    __syncthreads();
  }
  #pragma unroll
  for (int mi = 0; mi < 4; ++mi)
    #pragma unroll
    for (int ni = 0; ni < 4; ++ni)
      #pragma unroll
      for (int r = 0; r < 4; ++r) {
        const size_t row = m0 + wr * 64 + mi * 16 + hi * 4 + r;
        const size_t col = n0 + wc * 64 + ni * 16 + lo;
        if (OUTF32) Cf[row * N + col] = acc[mi][ni][r];
        else        Cb_[row * N + col] = (bf16)acc[mi][ni][r];
      }
}

// ---------------- causal flash attention fwd (v2) ----------------
// 4 waves/block, 64 q-rows per pass, TWO balanced passes (q-tile i and 31-i)
// per block -> uniform 33 KV-tiles/block (fixes the 2x scheduling tail).
// Swapped QK^T: s = mfma(K,Q) = S^T -> lane(lo) owns all S values of query
// q=lo  => in-lane softmax (2 shfl), scalar m/l, defer-rescale.
// P stored [q][kv] via packed ds_write_b64 with 16B-granular XOR swizzle.
__global__ __launch_bounds__(256) void flash_fwd(
    const bf16* __restrict__ Qg, const bf16* __restrict__ Kg,
    const bf16* __restrict__ Vg, bf16* __restrict__ Og) {
  const int t = threadIdx.x;
  const int wid = t >> 6, lane = t & 63, lo = lane & 15, hi = lane >> 4;
  const int h  = blockIdx.y;
  const int b  = blockIdx.z;

  __shared__ bf16 Ks[64 * 128];    // [kv][d]  swizzled (16 units/row, key kv&15)
  __shared__ bf16 Vt[128 * 64];    // [d][kv]  swizzled (key (d^(d>>3))&7)
  __shared__ bf16 Ps[4][16 * 64];  // per-wave P [q][kv], 16B-unit swizzle key q&7

  const size_t hoff = (size_t)b * SEQL * DM + (size_t)h * HD;
  const float SCALE_LOG2 = 0.12751743f;   // (1/sqrt(128)) * log2(e)

  const int krow = t >> 4;
  const int kul  = ((t & 15) ^ krow) * 8;
  const int vd0  = (t & 31) * 4;
  const int vg   = t >> 5;
  char* myP = (char*)(Ps[wid]);
  const f32x4 zero4 = {0.f, 0.f, 0.f, 0.f};

  #pragma unroll 1
  for (int pass = 0; pass < 2; ++pass) {
    const int q0 = (pass ? (31 - (int)blockIdx.x) : (int)blockIdx.x) * 64;

    // Q B-frags: col=q=q_base+lo, k-chunk kc*32+hi*8
    bf16x8 qf[4];
    {
      const bf16* qrow = Qg + hoff + (size_t)(q0 + wid * 16 + lo) * DM;
      #pragma unroll
      for (int kc = 0; kc < 4; ++kc)
        qf[kc] = *reinterpret_cast<const bf16x8*>(qrow + kc * 32 + hi * 8);
    }

    f32x4 acc[8];
    #pragma unroll
    for (int i = 0; i < 8; ++i) acc[i] = zero4;
    float m_run = -1e30f, l_run = 0.f;

    const int ntiles = q0 / 64 + 1;
    #pragma unroll 1
    for (int it = 0; it < ntiles; ++it) {
      const int kv0 = it * 64;
      // ---- stage K tile ----
      {
        const bf16* gK = Kg + hoff + (size_t)(kv0 + krow) * DM + kul;
        char* lK = (char*)Ks + wid * 1024;
        #pragma unroll
        for (int j = 0; j < 4; ++j)
          gload16(gK + (size_t)j * 16 * DM, lK + j * 4096);
      }
      // ---- stage V^T tile ----
      {
        const bf16* gV = Vg + hoff + (size_t)kv0 * DM + vd0;
        bf16x4 ld[8];
        #pragma unroll
        for (int e = 0; e < 8; ++e)
          ld[e] = *reinterpret_cast<const bf16x4*>(gV + (size_t)(vg * 8 + e) * DM);
        #pragma unroll
        for (int c = 0; c < 4; ++c) {
          const int d = vd0 + c;
          const int sw = (d ^ (d >> 3)) & 7;
          bf16x8 pk;
          #pragma unroll
          for (int e = 0; e < 8; ++e) pk[e] = ld[e][c];
          *reinterpret_cast<bf16x8*>(Vt + d * 64 + ((vg ^ sw) * 8)) = pk;
        }
      }
      __syncthreads();

      // ---- S^T = K Q^T (swapped operands): lane holds s[nf][r] for
      //      q = q0+wid*16+lo, kv = kv0 + nf*16 + hi*4 + r ----
      f32x4 s[4];
      #pragma unroll
      for (int nf = 0; nf < 4; ++nf) s[nf] = zero4;
      #pragma unroll
      for (int nf = 0; nf < 4; ++nf) {
        const bf16* krp = Ks + (nf * 16 + lo) * 128;
        #pragma unroll
        for (int kc = 0; kc < 4; ++kc) {
          const bf16x8 kb = *reinterpret_cast<const bf16x8*>(krp + (((kc * 4 + hi) ^ lo) * 8));
          s[nf] = mfma16(kb, qf[kc], s[nf]);
        }
      }
      // ---- scale(+log2e) + causal mask ----
      const bool boundary = (kv0 == q0);
      #pragma unroll
      for (int nf = 0; nf < 4; ++nf)
        #pragma unroll
        for (int r = 0; r < 4; ++r) {
          float v = s[nf][r] * SCALE_LOG2;
          if (boundary && (nf * 16 + hi * 4 + r > wid * 16 + lo)) v = -1e30f;
          s[nf][r] = v;
        }
      // ---- in-lane online softmax (per lane: q=lo row) ----
      float pmax = -1e30f;
      #pragma unroll
      for (int nf = 0; nf < 4; ++nf)
        #pragma unroll
        for (int r = 0; r < 4; ++r) pmax = fmaxf(pmax, s[nf][r]);
      pmax = fmaxf(pmax, __shfl_xor(pmax, 16, 64));
      pmax = fmaxf(pmax, __shfl_xor(pmax, 32, 64));
      float mnew = m_run;
      if (!__all(pmax <= m_run)) {
        mnew = fmaxf(m_run, pmax);
        const float fctr = exp2f(m_run - mnew);
        m_run = mnew;
        l_run *= fctr;
        float fa[4];
        #pragma unroll
        for (int r = 0; r < 4; ++r) fa[r] = __shfl(fctr, hi * 4 + r, 64);
        #pragma unroll
        for (int i = 0; i < 8; ++i)
          #pragma unroll
          for (int r = 0; r < 4; ++r) acc[i][r] *= fa[r];
      }
      float sum = 0.f;
      #pragma unroll
      for (int nf = 0; nf < 4; ++nf)
        #pragma unroll
        for (int r = 0; r < 4; ++r) {
          const float p = exp2f(s[nf][r] - mnew);
          s[nf][r] = p;
          sum += p;
        }
      sum += __shfl_xor(sum, 16, 64);
      sum += __shfl_xor(sum, 32, 64);
      l_run += sum;
      // ---- P -> LDS, packed b64 writes: row q=lo, kv=nf*16+hi*4+{0..3}
      //      16B-unit swizzle: U16' = U16 ^ (row&7) ----
      #pragma unroll
      for (int nf = 0; nf < 4; ++nf) {
        bf16x4 w;
        #pragma unroll
        for (int r = 0; r < 4; ++r) w[r] = (bf16)s[nf][r];
        *reinterpret_cast<bf16x4*>(myP + lo * 128 +
            (((nf * 2 + (hi >> 1)) ^ (lo & 7)) * 16) + (hi & 1) * 8) = w;
      }
      // ---- P A-frags: row q=lo, k = kc*32+hi*8+e ----
      bf16x8 pa[2];
      #pragma unroll
      for (int kc = 0; kc < 2; ++kc)
        pa[kc] = *reinterpret_cast<const bf16x8*>(myP + lo * 128 +
            (((kc * 4 + hi) ^ (lo & 7)) * 16));
      // ---- O += P V ----
      #pragma unroll
      for (int nf = 0; nf < 8; ++nf) {
        const int d = nf * 16 + lo;
        const int sw = (d ^ (d >> 3)) & 7;
        const bf16* vrp = Vt + d * 64;
        #pragma unroll
        for (int kc = 0; kc < 2; ++kc) {
          const bf16x8 bv = *reinterpret_cast<const bf16x8*>(vrp + (((kc * 4 + hi) ^ sw) * 8));
          acc[nf] = mfma16(pa[kc], bv, acc[nf]);
        }
      }
      __syncthreads();
    }

    // ---- finalize ----
    const float linv = 1.f / l_run;   // per lane: row q=lo
    float la[4];
    #pragma unroll
    for (int r = 0; r < 4; ++r) la[r] = __shfl(linv, hi * 4 + r, 64);
    #pragma unroll
    for (int nf = 0; nf < 8; ++nf)
      #pragma unroll
      for (int r = 0; r < 4; ++r) {
        const size_t row = q0 + wid * 16 + hi * 4 + r;
        Og[hoff + row * DM + nf * 16 + lo] = (bf16)(acc[nf][r] * la[r]);
      }
  }
}

extern "C" void kernel_launch(void* const* d_in, const int* in_sizes, int n_in,
                              void* d_out, int out_size, void* d_ws, size_t ws_size,
                              hipStream_t stream) {
  const float* x  = (const float*)d_in[0];
  const float* wq = (const float*)d_in[1];
  const float* wk = (const float*)d_in[2];
  const float* wv = (const float*)d_in[3];
  const float* wo = (const float*)d_in[4];
  const float* fc = (const float*)d_in[5];
  const float* fs = (const float*)d_in[6];
  float* out = (float*)d_out;

  char* ws = (char*)d_ws;
  bf16* xb    = (bf16*)ws;                      // 16MB  x bf16; reused as O
  bf16* wqkvt = (bf16*)(ws + (16ull << 20));    // 24MB
  bf16* wot   = (bf16*)(ws + (40ull << 20));    //  8MB
  bf16* qkv   = (bf16*)(ws + (48ull << 20));    // 48MB
  bf16* Qb = qkv;
  bf16* Kb = qkv + (size_t)MR * DM;
  bf16* Vb = qkv + 2 * (size_t)MR * DM;

  cvt_x<<<8192, 256, 0, stream>>>(x, xb);
  transpose_w<<<dim3(64, 64, 4), dim3(32, 8), 0, stream>>>(wq, wk, wv, wo, wqkvt, wot);
  gemm_bt<true, false><<<dim3(16, 32, 3), 256, 0, stream>>>(xb, wqkvt, qkv, nullptr, MR, DM, DM);
  rope_k<<<dim3(4096, 2), 256, 0, stream>>>(Qb, Kb, fc, fs);
  flash_fwd<<<dim3(16, 16, 2), 256, 0, stream>>>(Qb, Kb, Vb, xb /*O*/);
  gemm_bt<false, true><<<dim3(16, 32), 256, 0, stream>>>(xb, wot, nullptr, out, MR, DM, DM);
}

// Round 4
// 423.786 us; speedup vs baseline: 1.1951x; 1.0332x over previous
//
#include <hip/hip_runtime.h>
#include <hip/hip_bf16.h>

typedef __bf16 bf16;
typedef __attribute__((ext_vector_type(8))) __bf16 bf16x8;
typedef __attribute__((ext_vector_type(4))) __bf16 bf16x4;
typedef __attribute__((ext_vector_type(4))) float  f32x4;

typedef const void __attribute__((address_space(1)))* gas_t;
typedef void __attribute__((address_space(3)))* las_t;

__device__ __forceinline__ void gload16(const void* g, void* l) {
  __builtin_amdgcn_global_load_lds((gas_t)g, (las_t)l, 16, 0, 0);
}
__device__ __forceinline__ f32x4 mfma16(bf16x8 a, bf16x8 b, f32x4 c) {
  return __builtin_amdgcn_mfma_f32_16x16x32_bf16(a, b, c, 0, 0, 0);
}

constexpr int SEQL = 2048;
constexpr int DM   = 2048;   // model dim
constexpr int HD   = 128;    // head dim
constexpr int MR   = 4096;   // B*S rows

// ---------------- fp32 -> bf16 convert (x) ----------------
__global__ __launch_bounds__(256) void cvt_x(const float* __restrict__ x,
                                             bf16* __restrict__ xb) {
  const size_t i = ((size_t)blockIdx.x * 256 + threadIdx.x) * 4;
  const f32x4 v = *reinterpret_cast<const f32x4*>(x + i);
  bf16x4 o;
  #pragma unroll
  for (int j = 0; j < 4; ++j) o[j] = (bf16)v[j];
  *reinterpret_cast<bf16x4*>(xb + i) = o;
}

// ---------------- weight transpose + convert: [K][N] f32 -> [N][K] bf16 ----------------
__global__ __launch_bounds__(256) void transpose_w(
    const float* __restrict__ w0, const float* __restrict__ w1,
    const float* __restrict__ w2, const float* __restrict__ w3,
    bf16* __restrict__ wqkvt, bf16* __restrict__ wot) {
  const int z = blockIdx.z;
  const float* src = (z == 0) ? w0 : (z == 1) ? w1 : (z == 2) ? w2 : w3;
  bf16* dst = (z < 3) ? (wqkvt + (size_t)z * DM * DM) : wot;
  __shared__ float tile[32][33];
  const int tx = threadIdx.x, ty = threadIdx.y;
  const int x0 = blockIdx.x * 32, y0 = blockIdx.y * 32;
  #pragma unroll
  for (int i = 0; i < 4; ++i)
    tile[ty + 8 * i][tx] = src[(size_t)(y0 + ty + 8 * i) * DM + x0 + tx];
  __syncthreads();
  #pragma unroll
  for (int i = 0; i < 4; ++i)
    dst[(size_t)(x0 + ty + 8 * i) * DM + y0 + tx] = (bf16)tile[tx][ty + 8 * i];
}

// ---------------- RoPE (in-place on Q and K, bf16) ----------------
__global__ __launch_bounds__(256) void rope_k(bf16* __restrict__ Q,
                                              bf16* __restrict__ Kk,
                                              const float* __restrict__ fc,
                                              const float* __restrict__ fs) {
  bf16* X = blockIdx.y ? Kk : Q;
  const size_t tid = (size_t)blockIdx.x * 256 + threadIdx.x;
  const size_t e0 = tid * 8;                 // 8 bf16 = 4 rot pairs
  const int col = (int)(e0 & (DM - 1));
  const int row = (int)(e0 >> 11);
  const int s   = row & (SEQL - 1);
  const int p0  = (col & (HD - 1)) >> 1;     // pair index, multiple of 4
  bf16x8 v = *reinterpret_cast<bf16x8*>(X + e0);
  const f32x4 c  = *reinterpret_cast<const f32x4*>(fc + (size_t)s * 64 + p0);
  const f32x4 sn = *reinterpret_cast<const f32x4*>(fs + (size_t)s * 64 + p0);
  #pragma unroll
  for (int j = 0; j < 4; ++j) {
    const float x0 = (float)v[2 * j], x1 = (float)v[2 * j + 1];
    v[2 * j]     = (bf16)(x0 * c[j] - x1 * sn[j]);
    v[2 * j + 1] = (bf16)(x0 * sn[j] + x1 * c[j]);
  }
  *reinterpret_cast<bf16x8*>(X + e0) = v;
}

// ================= 256x256 8-phase bf16 GEMM (T2+T3+T4+T5) =================
// C[M][N] = A[M][K] * Bt[N][K]^T.  512 thr / 8 waves (2M x 4N), BK=64,
// LDS 128 KiB = 2 buf x {A,B} x 2 halves x (128 rows x 64 k) bf16.
// Staging: global_load_lds w=16, linear LDS dest, involutive XOR swizzle
// unit^=(row&7) applied on the global source AND the ds_read address.
// Schedule: per K-tile 4 phases (A-quadrants of 32 rows); B-frags read once
// (phase 0) and held in registers. Half-tile issue lead = 7; counted
// vmcnt(6) only at the last phase of each K-tile (3 half-tiles in flight).
#define GPH(Q, STAGE, TAIL)                                                    \
  {                                                                            \
    const char* ap = aB + ((Q) * 32 + lo) * 128;                               \
    const bf16x8 a00 = *(const bf16x8*)(ap + su0);                             \
    const bf16x8 a01 = *(const bf16x8*)(ap + su1);                             \
    const bf16x8 a10 = *(const bf16x8*)(ap + 2048 + su0);                      \
    const bf16x8 a11 = *(const bf16x8*)(ap + 2048 + su1);                      \
    STAGE                                                                      \
    __builtin_amdgcn_s_barrier();                                              \
    asm volatile("s_waitcnt lgkmcnt(0)" ::: "memory");                         \
    __builtin_amdgcn_s_setprio(1);                                             \
    _Pragma("unroll")                                                          \
    for (int nf = 0; nf < 4; ++nf) {                                           \
      acc[2 * (Q)][nf]     = mfma16(a00, bfr[nf][0], acc[2 * (Q)][nf]);        \
      acc[2 * (Q)][nf]     = mfma16(a01, bfr[nf][1], acc[2 * (Q)][nf]);        \
      acc[2 * (Q) + 1][nf] = mfma16(a10, bfr[nf][0], acc[2 * (Q) + 1][nf]);    \
      acc[2 * (Q) + 1][nf] = mfma16(a11, bfr[nf][1], acc[2 * (Q) + 1][nf]);    \
    }                                                                          \
    __builtin_amdgcn_s_setprio(0);                                             \
    TAIL                                                                       \
    __builtin_amdgcn_s_barrier();                                              \
    asm volatile("" ::: "memory");                                             \
  }

template <bool MULTI>
__global__ __launch_bounds__(512, 2) void gemm8(
    const bf16* __restrict__ A, const bf16* __restrict__ Bt,
    bf16* __restrict__ Cb, const int M, const int N, const int K) {
  __shared__ __attribute__((aligned(16))) char lds[131072];
  const int t = threadIdx.x;
  const int wid = t >> 6, lane = t & 63, lo = lane & 15, hi = lane >> 4;
  const int wm = wid >> 2, wn = wid & 3;

  const int bid = blockIdx.x;
  const int nx = bid & 7;
  const int my = MULTI ? ((bid >> 3) & 15) : (bid >> 3);
  const int z  = MULTI ? (bid >> 7) : 0;
  const int m0 = my * 256, n0 = nx * 256;
  const bf16* Bt_ = Bt + (MULTI ? (size_t)z * N * K : 0);
  bf16* Cb_ = Cb + (MULTI ? (size_t)z * M * N : 0);

  // staging constants: thread covers 16B unit u = wid*64+lane (+512 for j=1)
  const int urow  = (wid << 3) + (lane >> 3);            // row-in-64-chunk
  const int uunit = (lane & 7) ^ ((lane >> 3) & 7);      // pre-swizzled source
  const bf16* gA = A   + (size_t)(m0 + urow) * K + uunit * 8;
  const bf16* gB = Bt_ + (size_t)(n0 + urow) * K + uunit * 8;
  char* lw = lds + wid * 1024;

  const int NT = K >> 6;

  auto stg = [&](const bf16* gbase, int buf, int op, int h, int kt) {
    const bf16* g = gbase + (size_t)(h * 128) * K + kt * 64;
    char* l = lw + (((buf << 1) | op) * 2 + h) * 16384;
    gload16(g, l);
    gload16(g + (size_t)64 * K, l + 8192);
  };
  auto stB0 = [&](int kt2) { stg(gB, kt2 & 1, 1, 0, kt2); };
  auto stB1 = [&](int kt2) { stg(gB, kt2 & 1, 1, 1, kt2); };
  auto stA0 = [&](int kt2) { stg(gA, kt2 & 1, 0, 0, kt2); };
  auto stA1 = [&](int kt2) { stg(gA, kt2 & 1, 0, 1, kt2); };

  f32x4 acc[8][4];
  #pragma unroll
  for (int i = 0; i < 8; ++i)
    #pragma unroll
    for (int j = 0; j < 4; ++j) acc[i][j] = (f32x4){0.f, 0.f, 0.f, 0.f};

  const int su0 = (hi ^ (lo & 7)) * 16;         // k-step 0 swizzled unit
  const int su1 = ((4 + hi) ^ (lo & 7)) * 16;   // k-step 1

  // prologue: tile0 {B0,B1,A0,A1} + tile1 {B0,B1,A0}  (14 loads)
  stB0(0); stB1(0); stA0(0); stA1(0);
  stB0(1); stB1(1); stA0(1);
  asm volatile("s_waitcnt vmcnt(6)" ::: "memory");   // tile0 complete
  __builtin_amdgcn_s_barrier();
  asm volatile("" ::: "memory");

  #pragma unroll 1
  for (int kt = 0; kt < NT; ++kt) {
    const int bufc = kt & 1;
    const char* aB = lds + ((bufc * 2 + 0) * 2 + wm) * 16384;
    const char* bB = lds + ((bufc * 2 + 1) * 2 + (wn >> 1)) * 16384;
    bf16x8 bfr[4][2];
    {  // B-frags for the whole K-tile (read once, kept in registers)
      const char* bp = bB + ((wn & 1) * 64 + lo) * 128;
      #pragma unroll
      for (int nf = 0; nf < 4; ++nf) {
        bfr[nf][0] = *(const bf16x8*)(bp + nf * 2048 + su0);
        bfr[nf][1] = *(const bf16x8*)(bp + nf * 2048 + su1);
      }
    }
    GPH(0, if (kt + 1 < NT) stA1(kt + 1);, )
    GPH(1, if (kt + 2 < NT) stB0(kt + 2);, )
    GPH(2, if (kt + 2 < NT) stB1(kt + 2);, )
    GPH(3, if (kt + 2 < NT) stA0(kt + 2);,
        if (kt + 2 < NT) { asm volatile("s_waitcnt vmcnt(6)" ::: "memory"); }
        else             { asm volatile("s_waitcnt vmcnt(0)" ::: "memory"); })
  }

  // epilogue: C/D layout col=lane&15, row=(lane>>4)*4+r  [verified m89/m91]
  #pragma unroll
  for (int mf = 0; mf < 8; ++mf)
    #pragma unroll
    for (int nf = 0; nf < 4; ++nf)
      #pragma unroll
      for (int r = 0; r < 4; ++r) {
        const size_t row = m0 + wm * 128 + mf * 16 + hi * 4 + r;
        const size_t col = n0 + wn * 64 + nf * 16 + lo;
        Cb_[row * N + col] = (bf16)acc[mf][nf][r];
      }
}

// ---------------- m97-style bf16 GEMM (kept for out-proj) ----------------
__global__ __launch_bounds__(256) void gemm_bt_f32(
    const bf16* __restrict__ A, const bf16* __restrict__ Bt,
    float* __restrict__ Cf, const int M, const int N, const int K) {
  const int t = threadIdx.x;
  const int wid = t >> 6, lane = t & 63, lo = lane & 15, hi = lane >> 4;
  const int m0 = blockIdx.y * 128, n0 = blockIdx.x * 128;
  __shared__ bf16 As[128 * 32];
  __shared__ bf16 Bs[128 * 32];
  const int wr = wid >> 1, wc = wid & 1;
  const f32x4 zero4 = {0.f, 0.f, 0.f, 0.f};
  f32x4 acc[4][4];
  #pragma unroll
  for (int i = 0; i < 4; ++i)
    #pragma unroll
    for (int j = 0; j < 4; ++j) acc[i][j] = zero4;

  const int r_a = t >> 2;
  const int ul  = ((t & 3) ^ (r_a & 3)) * 8;
  const bf16* gA0 = A  + (size_t)(m0 + r_a) * K + ul;
  const bf16* gB0 = Bt + (size_t)(n0 + r_a) * K + ul;
  char* lA = (char*)As + wid * 1024;
  char* lB = (char*)Bs + wid * 1024;

  const int ru = (hi ^ (lo & 3)) * 8;

  for (int k0 = 0; k0 < K; k0 += 32) {
    gload16(gA0 + k0, lA);
    gload16(gA0 + (size_t)64 * K + k0, lA + 4096);
    gload16(gB0 + k0, lB);
    gload16(gB0 + (size_t)64 * K + k0, lB + 4096);
    __syncthreads();
    bf16x8 af[4], bb[4];
    #pragma unroll
    for (int i = 0; i < 4; ++i)
      af[i] = *reinterpret_cast<const bf16x8*>(As + (wr * 64 + i * 16 + lo) * 32 + ru);
    #pragma unroll
    for (int i = 0; i < 4; ++i)
      bb[i] = *reinterpret_cast<const bf16x8*>(Bs + (wc * 64 + i * 16 + lo) * 32 + ru);
    #pragma unroll
    for (int mi = 0; mi < 4; ++mi)
      #pragma unroll
      for (int ni = 0; ni < 4; ++ni)
        acc[mi][ni] = mfma16(af[mi], bb[ni], acc[mi][ni]);
    __syncthreads();
  }
  #pragma unroll
  for (int mi = 0; mi < 4; ++mi)
    #pragma unroll
    for (int ni = 0; ni < 4; ++ni)
      #pragma unroll
      for (int r = 0; r < 4; ++r) {
        const size_t row = m0 + wr * 64 + mi * 16 + hi * 4 + r;
        const size_t col = n0 + wc * 64 + ni * 16 + lo;
        Cf[row * N + col] = acc[mi][ni][r];
      }
}

// ---------------- causal flash attention fwd (v2) ----------------
__global__ __launch_bounds__(256) void flash_fwd(
    const bf16* __restrict__ Qg, const bf16* __restrict__ Kg,
    const bf16* __restrict__ Vg, bf16* __restrict__ Og) {
  const int t = threadIdx.x;
  const int wid = t >> 6, lane = t & 63, lo = lane & 15, hi = lane >> 4;
  const int h  = blockIdx.y;
  const int b  = blockIdx.z;

  __shared__ bf16 Ks[64 * 128];    // [kv][d]  swizzled (16 units/row, key kv&15)
  __shared__ bf16 Vt[128 * 64];    // [d][kv]  swizzled (key (d^(d>>3))&7)
  __shared__ bf16 Ps[4][16 * 64];  // per-wave P [q][kv], 16B-unit swizzle key q&7

  const size_t hoff = (size_t)b * SEQL * DM + (size_t)h * HD;
  const float SCALE_LOG2 = 0.12751743f;   // (1/sqrt(128)) * log2(e)

  const int krow = t >> 4;
  const int kul  = ((t & 15) ^ krow) * 8;
  const int vd0  = (t & 31) * 4;
  const int vg   = t >> 5;
  char* myP = (char*)(Ps[wid]);
  const f32x4 zero4 = {0.f, 0.f, 0.f, 0.f};

  #pragma unroll 1
  for (int pass = 0; pass < 2; ++pass) {
    const int q0 = (pass ? (31 - (int)blockIdx.x) : (int)blockIdx.x) * 64;

    bf16x8 qf[4];
    {
      const bf16* qrow = Qg + hoff + (size_t)(q0 + wid * 16 + lo) * DM;
      #pragma unroll
      for (int kc = 0; kc < 4; ++kc)
        qf[kc] = *reinterpret_cast<const bf16x8*>(qrow + kc * 32 + hi * 8);
    }

    f32x4 acc[8];
    #pragma unroll
    for (int i = 0; i < 8; ++i) acc[i] = zero4;
    float m_run = -1e30f, l_run = 0.f;

    const int ntiles = q0 / 64 + 1;
    #pragma unroll 1
    for (int it = 0; it < ntiles; ++it) {
      const int kv0 = it * 64;
      {
        const bf16* gK = Kg + hoff + (size_t)(kv0 + krow) * DM + kul;
        char* lK = (char*)Ks + wid * 1024;
        #pragma unroll
        for (int j = 0; j < 4; ++j)
          gload16(gK + (size_t)j * 16 * DM, lK + j * 4096);
      }
      {
        const bf16* gV = Vg + hoff + (size_t)kv0 * DM + vd0;
        bf16x4 ld[8];
        #pragma unroll
        for (int e = 0; e < 8; ++e)
          ld[e] = *reinterpret_cast<const bf16x4*>(gV + (size_t)(vg * 8 + e) * DM);
        #pragma unroll
        for (int c = 0; c < 4; ++c) {
          const int d = vd0 + c;
          const int sw = (d ^ (d >> 3)) & 7;
          bf16x8 pk;
          #pragma unroll
          for (int e = 0; e < 8; ++e) pk[e] = ld[e][c];
          *reinterpret_cast<bf16x8*>(Vt + d * 64 + ((vg ^ sw) * 8)) = pk;
        }
      }
      __syncthreads();

      f32x4 s[4];
      #pragma unroll
      for (int nf = 0; nf < 4; ++nf) s[nf] = zero4;
      #pragma unroll
      for (int nf = 0; nf < 4; ++nf) {
        const bf16* krp = Ks + (nf * 16 + lo) * 128;
        #pragma unroll
        for (int kc = 0; kc < 4; ++kc) {
          const bf16x8 kb = *reinterpret_cast<const bf16x8*>(krp + (((kc * 4 + hi) ^ lo) * 8));
          s[nf] = mfma16(kb, qf[kc], s[nf]);
        }
      }
      const bool boundary = (kv0 == q0);
      #pragma unroll
      for (int nf = 0; nf < 4; ++nf)
        #pragma unroll
        for (int r = 0; r < 4; ++r) {
          float v = s[nf][r] * SCALE_LOG2;
          if (boundary && (nf * 16 + hi * 4 + r > wid * 16 + lo)) v = -1e30f;
          s[nf][r] = v;
        }
      float pmax = -1e30f;
      #pragma unroll
      for (int nf = 0; nf < 4; ++nf)
        #pragma unroll
        for (int r = 0; r < 4; ++r) pmax = fmaxf(pmax, s[nf][r]);
      pmax = fmaxf(pmax, __shfl_xor(pmax, 16, 64));
      pmax = fmaxf(pmax, __shfl_xor(pmax, 32, 64));
      float mnew = m_run;
      if (!__all(pmax <= m_run)) {
        mnew = fmaxf(m_run, pmax);
        const float fctr = exp2f(m_run - mnew);
        m_run = mnew;
        l_run *= fctr;
        float fa[4];
        #pragma unroll
        for (int r = 0; r < 4; ++r) fa[r] = __shfl(fctr, hi * 4 + r, 64);
        #pragma unroll
        for (int i = 0; i < 8; ++i)
          #pragma unroll
          for (int r = 0; r < 4; ++r) acc[i][r] *= fa[r];
      }
      float sum = 0.f;
      #pragma unroll
      for (int nf = 0; nf < 4; ++nf)
        #pragma unroll
        for (int r = 0; r < 4; ++r) {
          const float p = exp2f(s[nf][r] - mnew);
          s[nf][r] = p;
          sum += p;
        }
      sum += __shfl_xor(sum, 16, 64);
      sum += __shfl_xor(sum, 32, 64);
      l_run += sum;
      #pragma unroll
      for (int nf = 0; nf < 4; ++nf) {
        bf16x4 w;
        #pragma unroll
        for (int r = 0; r < 4; ++r) w[r] = (bf16)s[nf][r];
        *reinterpret_cast<bf16x4*>(myP + lo * 128 +
            (((nf * 2 + (hi >> 1)) ^ (lo & 7)) * 16) + (hi & 1) * 8) = w;
      }
      bf16x8 pa[2];
      #pragma unroll
      for (int kc = 0; kc < 2; ++kc)
        pa[kc] = *reinterpret_cast<const bf16x8*>(myP + lo * 128 +
            (((kc * 4 + hi) ^ (lo & 7)) * 16));
      #pragma unroll
      for (int nf = 0; nf < 8; ++nf) {
        const int d = nf * 16 + lo;
        const int sw = (d ^ (d >> 3)) & 7;
        const bf16* vrp = Vt + d * 64;
        #pragma unroll
        for (int kc = 0; kc < 2; ++kc) {
          const bf16x8 bv = *reinterpret_cast<const bf16x8*>(vrp + (((kc * 4 + hi) ^ sw) * 8));
          acc[nf] = mfma16(pa[kc], bv, acc[nf]);
        }
      }
      __syncthreads();
    }

    const float linv = 1.f / l_run;
    float la[4];
    #pragma unroll
    for (int r = 0; r < 4; ++r) la[r] = __shfl(linv, hi * 4 + r, 64);
    #pragma unroll
    for (int nf = 0; nf < 8; ++nf)
      #pragma unroll
      for (int r = 0; r < 4; ++r) {
        const size_t row = q0 + wid * 16 + hi * 4 + r;
        Og[hoff + row * DM + nf * 16 + lo] = (bf16)(acc[nf][r] * la[r]);
      }
  }
}

extern "C" void kernel_launch(void* const* d_in, const int* in_sizes, int n_in,
                              void* d_out, int out_size, void* d_ws, size_t ws_size,
                              hipStream_t stream) {
  const float* x  = (const float*)d_in[0];
  const float* wq = (const float*)d_in[1];
  const float* wk = (const float*)d_in[2];
  const float* wv = (const float*)d_in[3];
  const float* wo = (const float*)d_in[4];
  const float* fc = (const float*)d_in[5];
  const float* fs = (const float*)d_in[6];
  float* out = (float*)d_out;

  char* ws = (char*)d_ws;
  bf16* xb    = (bf16*)ws;                      // 16MB  x bf16; reused as O
  bf16* wqkvt = (bf16*)(ws + (16ull << 20));    // 24MB
  bf16* wot   = (bf16*)(ws + (40ull << 20));    //  8MB
  bf16* qkv   = (bf16*)(ws + (48ull << 20));    // 48MB
  bf16* Qb = qkv;
  bf16* Kb = qkv + (size_t)MR * DM;
  bf16* Vb = qkv + 2 * (size_t)MR * DM;

  cvt_x<<<8192, 256, 0, stream>>>(x, xb);
  transpose_w<<<dim3(64, 64, 4), dim3(32, 8), 0, stream>>>(wq, wk, wv, wo, wqkvt, wot);
  gemm8<true><<<384, 512, 0, stream>>>(xb, wqkvt, qkv, MR, DM, DM);
  rope_k<<<dim3(4096, 2), 256, 0, stream>>>(Qb, Kb, fc, fs);
  flash_fwd<<<dim3(16, 16, 2), 256, 0, stream>>>(Qb, Kb, Vb, xb /*O*/);
  gemm_bt_f32<<<dim3(16, 32), 256, 0, stream>>>(xb, wot, out, MR, DM, DM);
}

// Round 5
// 418.958 us; speedup vs baseline: 1.2088x; 1.0115x over previous
//
#include <hip/hip_runtime.h>
#include <hip/hip_bf16.h>

typedef __bf16 bf16;
typedef __attribute__((ext_vector_type(8))) __bf16 bf16x8;
typedef __attribute__((ext_vector_type(4))) __bf16 bf16x4;
typedef __attribute__((ext_vector_type(4))) float  f32x4;

typedef const void __attribute__((address_space(1)))* gas_t;
typedef void __attribute__((address_space(3)))* las_t;

__device__ __forceinline__ void gload16(const void* g, void* l) {
  __builtin_amdgcn_global_load_lds((gas_t)g, (las_t)l, 16, 0, 0);
}
__device__ __forceinline__ f32x4 mfma16(bf16x8 a, bf16x8 b, f32x4 c) {
  return __builtin_amdgcn_mfma_f32_16x16x32_bf16(a, b, c, 0, 0, 0);
}
#define BARRIER() do { asm volatile("" ::: "memory"); \
  __builtin_amdgcn_s_barrier(); asm volatile("" ::: "memory"); } while (0)

constexpr int SEQL = 2048;
constexpr int DM   = 2048;   // model dim
constexpr int HD   = 128;    // head dim
constexpr int MR   = 4096;   // B*S rows

// ---------------- fp32 -> bf16 convert (x) ----------------
__global__ __launch_bounds__(256) void cvt_x(const float* __restrict__ x,
                                             bf16* __restrict__ xb) {
  const size_t i = ((size_t)blockIdx.x * 256 + threadIdx.x) * 4;
  const f32x4 v = *reinterpret_cast<const f32x4*>(x + i);
  bf16x4 o;
  #pragma unroll
  for (int j = 0; j < 4; ++j) o[j] = (bf16)v[j];
  *reinterpret_cast<bf16x4*>(xb + i) = o;
}

// ---------------- weight transpose + convert: [K][N] f32 -> [N][K] bf16 ----------------
__global__ __launch_bounds__(256) void transpose_w(
    const float* __restrict__ w0, const float* __restrict__ w1,
    const float* __restrict__ w2, const float* __restrict__ w3,
    bf16* __restrict__ wqkvt, bf16* __restrict__ wot) {
  const int z = blockIdx.z;
  const float* src = (z == 0) ? w0 : (z == 1) ? w1 : (z == 2) ? w2 : w3;
  bf16* dst = (z < 3) ? (wqkvt + (size_t)z * DM * DM) : wot;
  __shared__ float tile[32][33];
  const int tx = threadIdx.x, ty = threadIdx.y;
  const int x0 = blockIdx.x * 32, y0 = blockIdx.y * 32;
  #pragma unroll
  for (int i = 0; i < 4; ++i)
    tile[ty + 8 * i][tx] = src[(size_t)(y0 + ty + 8 * i) * DM + x0 + tx];
  __syncthreads();
  #pragma unroll
  for (int i = 0; i < 4; ++i)
    dst[(size_t)(x0 + ty + 8 * i) * DM + y0 + tx] = (bf16)tile[tx][ty + 8 * i];
}

// ---------------- RoPE (in-place on Q and K, bf16) ----------------
__global__ __launch_bounds__(256) void rope_k(bf16* __restrict__ Q,
                                              bf16* __restrict__ Kk,
                                              const float* __restrict__ fc,
                                              const float* __restrict__ fs) {
  bf16* X = blockIdx.y ? Kk : Q;
  const size_t tid = (size_t)blockIdx.x * 256 + threadIdx.x;
  const size_t e0 = tid * 8;
  const int col = (int)(e0 & (DM - 1));
  const int row = (int)(e0 >> 11);
  const int s   = row & (SEQL - 1);
  const int p0  = (col & (HD - 1)) >> 1;
  bf16x8 v = *reinterpret_cast<bf16x8*>(X + e0);
  const f32x4 c  = *reinterpret_cast<const f32x4*>(fc + (size_t)s * 64 + p0);
  const f32x4 sn = *reinterpret_cast<const f32x4*>(fs + (size_t)s * 64 + p0);
  #pragma unroll
  for (int j = 0; j < 4; ++j) {
    const float x0 = (float)v[2 * j], x1 = (float)v[2 * j + 1];
    v[2 * j]     = (bf16)(x0 * c[j] - x1 * sn[j]);
    v[2 * j + 1] = (bf16)(x0 * sn[j] + x1 * c[j]);
  }
  *reinterpret_cast<bf16x8*>(X + e0) = v;
}

// ================= 256x256 8-phase bf16 GEMM rev2 =================
// C[M][N] = A[M][K]*Bt[N][K]^T, Bt has 3 stacked weight mats (z).
// 512 thr / 8 waves (2M x 4N), BK=64, LDS 128 KiB (2dbuf x {A,B} x 2 half).
// rev2: A-frags software-pipelined across phases (no forced lgkmcnt(0));
// steady-state vmcnt(4) at ph3-start + barrier (cross-wave sound), so the
// awaited loads always have >= 4-phase lead; XCD swizzle pins 2 A-panels
// (2 MB) per XCD L2. Involutive XOR swizzle unit^=(row&7) both sides.
#define LDA4(DST, BASE, ROWOFF)                                                \
  {                                                                            \
    const char* ap_ = (BASE) + ((ROWOFF) + lo) * 128;                          \
    DST[0] = *(const bf16x8*)(ap_ + su0);                                      \
    DST[1] = *(const bf16x8*)(ap_ + su1);                                      \
    DST[2] = *(const bf16x8*)(ap_ + 2048 + su0);                               \
    DST[3] = *(const bf16x8*)(ap_ + 2048 + su1);                               \
  }
#define MFMAQ(Q, AR)                                                           \
  {                                                                            \
    __builtin_amdgcn_s_setprio(1);                                             \
    _Pragma("unroll")                                                          \
    for (int nf = 0; nf < 4; ++nf) {                                           \
      acc[2 * (Q)][nf]     = mfma16(AR[0], bfr[nf][0], acc[2 * (Q)][nf]);      \
      acc[2 * (Q)][nf]     = mfma16(AR[1], bfr[nf][1], acc[2 * (Q)][nf]);      \
      acc[2 * (Q) + 1][nf] = mfma16(AR[2], bfr[nf][0], acc[2 * (Q) + 1][nf]);  \
      acc[2 * (Q) + 1][nf] = mfma16(AR[3], bfr[nf][1], acc[2 * (Q) + 1][nf]);  \
    }                                                                          \
    __builtin_amdgcn_s_setprio(0);                                             \
  }

__global__ __launch_bounds__(512, 2) void gemm8(
    const bf16* __restrict__ A, const bf16* __restrict__ Bt,
    bf16* __restrict__ Cb, const int M, const int N, const int K) {
  __shared__ __attribute__((aligned(16))) char lds[131072];
  const int t = threadIdx.x;
  const int wid = t >> 6, lane = t & 63, lo = lane & 15, hi = lane >> 4;
  const int wm = wid >> 2, wn = wid & 3;

  // XCD-aware swizzle (384 = 8 xcd * 2 my * 24 nxz): A-panels L2-resident
  const int bid = blockIdx.x;
  const int xcd = bid & 7, idx = bid >> 3;
  const int my = (xcd << 1) | (idx & 1);
  const int nxz = idx >> 1;
  const int nx = nxz & 7, z = nxz >> 3;
  const int m0 = my * 256, n0 = nx * 256;
  const bf16* Bt_ = Bt + (size_t)z * N * K;
  bf16* Cb_ = Cb + (size_t)z * M * N;

  const int urow  = (wid << 3) + (lane >> 3);
  const int uunit = (lane & 7) ^ ((lane >> 3) & 7);
  const bf16* gA = A   + (size_t)(m0 + urow) * K + uunit * 8;
  const bf16* gB = Bt_ + (size_t)(n0 + urow) * K + uunit * 8;
  char* lw = lds + wid * 1024;
  const int NT = K >> 6;

  auto stg = [&](const bf16* gbase, int buf, int op, int h, int kt) {
    const bf16* g = gbase + (size_t)(h * 128) * K + kt * 64;
    char* l = lw + (((buf << 1) | op) * 2 + h) * 16384;
    gload16(g, l);
    gload16(g + (size_t)64 * K, l + 8192);
  };
  auto stB0 = [&](int k2) { stg(gB, k2 & 1, 1, 0, k2); };
  auto stB1 = [&](int k2) { stg(gB, k2 & 1, 1, 1, k2); };
  auto stA0 = [&](int k2) { stg(gA, k2 & 1, 0, 0, k2); };
  auto stA1 = [&](int k2) { stg(gA, k2 & 1, 0, 1, k2); };

  f32x4 acc[8][4];
  #pragma unroll
  for (int i = 0; i < 8; ++i)
    #pragma unroll
    for (int j = 0; j < 4; ++j) acc[i][j] = (f32x4){0.f, 0.f, 0.f, 0.f};

  const int su0 = (hi ^ (lo & 7)) * 16;
  const int su1 = ((4 + hi) ^ (lo & 7)) * 16;

  // prologue: tile0 + tile1 fully issued; wait tile0 only
  stB0(0); stB1(0); stA0(0); stA1(0);
  stB0(1); stB1(1); stA0(1); stA1(1);
  asm volatile("s_waitcnt vmcnt(8)" ::: "memory");
  BARRIER();

  bf16x8 aP0[4], aP1[4];
  LDA4(aP0, lds + wm * 16384, 0);   // tile0 q0 (buf0 A half wm)

  #pragma unroll 1
  for (int kt = 0; kt < NT; ++kt) {
    const int bc = kt & 1;
    const char* aB = lds + (bc * 4 + wm) * 16384;
    const char* bB = lds + ((bc * 2 + 1) * 2 + (wn >> 1)) * 16384;
    const char* aN = lds + (((kt + 1) & 1) * 4 + wm) * 16384;
    bf16x8 bfr[4][2];
    {
      const char* bp = bB + ((wn & 1) * 64 + lo) * 128;
      #pragma unroll
      for (int nf = 0; nf < 4; ++nf) {
        bfr[nf][0] = *(const bf16x8*)(bp + nf * 2048 + su0);
        bfr[nf][1] = *(const bf16x8*)(bp + nf * 2048 + su1);
      }
    }
    // ph0: MFMA q0 (aP0), prefetch q1
    LDA4(aP1, aB, 32);
    BARRIER();
    MFMAQ(0, aP0)
    BARRIER();
    // ph1: MFMA q1 (aP1), prefetch q2, stage B0(t+2)
    LDA4(aP0, aB, 64);
    if (kt + 2 < NT) stB0(kt + 2);
    BARRIER();
    MFMAQ(1, aP1)
    BARRIER();
    // ph2: MFMA q2 (aP0), prefetch q3, stage B1(t+2)
    LDA4(aP1, aB, 96);
    if (kt + 2 < NT) stB1(kt + 2);
    BARRIER();
    MFMAQ(2, aP0)
    BARRIER();
    // ph3: vmcnt + barrier (tile t+1 A/B landed, cross-wave), prefetch next
    //      tile q0, stage A(t+2), MFMA q3 (aP1)
    if (kt + 2 < NT)      { asm volatile("s_waitcnt vmcnt(4)" ::: "memory"); }
    else if (kt + 1 < NT) { asm volatile("s_waitcnt vmcnt(0)" ::: "memory"); }
    BARRIER();
    if (kt + 1 < NT) LDA4(aP0, aN, 0);
    if (kt + 2 < NT) { stA0(kt + 2); stA1(kt + 2); }
    MFMAQ(3, aP1)
    BARRIER();
  }

  // epilogue: C/D layout col=lane&15, row=(lane>>4)*4+r  [verified m89/m91]
  #pragma unroll
  for (int mf = 0; mf < 8; ++mf)
    #pragma unroll
    for (int nf = 0; nf < 4; ++nf)
      #pragma unroll
      for (int r = 0; r < 4; ++r) {
        const size_t row = m0 + wm * 128 + mf * 16 + hi * 4 + r;
        const size_t col = n0 + wn * 64 + nf * 16 + lo;
        Cb_[row * N + col] = (bf16)acc[mf][nf][r];
      }
}

// ---------------- m97-style bf16 GEMM (out-proj, f32 out) ----------------
__global__ __launch_bounds__(256) void gemm_bt_f32(
    const bf16* __restrict__ A, const bf16* __restrict__ Bt,
    float* __restrict__ Cf, const int M, const int N, const int K) {
  const int t = threadIdx.x;
  const int wid = t >> 6, lane = t & 63, lo = lane & 15, hi = lane >> 4;
  const int m0 = blockIdx.y * 128, n0 = blockIdx.x * 128;
  __shared__ bf16 As[128 * 32];
  __shared__ bf16 Bs[128 * 32];
  const int wr = wid >> 1, wc = wid & 1;
  const f32x4 zero4 = {0.f, 0.f, 0.f, 0.f};
  f32x4 acc[4][4];
  #pragma unroll
  for (int i = 0; i < 4; ++i)
    #pragma unroll
    for (int j = 0; j < 4; ++j) acc[i][j] = zero4;

  const int r_a = t >> 2;
  const int ul  = ((t & 3) ^ (r_a & 3)) * 8;
  const bf16* gA0 = A  + (size_t)(m0 + r_a) * K + ul;
  const bf16* gB0 = Bt + (size_t)(n0 + r_a) * K + ul;
  char* lA = (char*)As + wid * 1024;
  char* lB = (char*)Bs + wid * 1024;

  const int ru = (hi ^ (lo & 3)) * 8;

  for (int k0 = 0; k0 < K; k0 += 32) {
    gload16(gA0 + k0, lA);
    gload16(gA0 + (size_t)64 * K + k0, lA + 4096);
    gload16(gB0 + k0, lB);
    gload16(gB0 + (size_t)64 * K + k0, lB + 4096);
    __syncthreads();
    bf16x8 af[4], bb[4];
    #pragma unroll
    for (int i = 0; i < 4; ++i)
      af[i] = *reinterpret_cast<const bf16x8*>(As + (wr * 64 + i * 16 + lo) * 32 + ru);
    #pragma unroll
    for (int i = 0; i < 4; ++i)
      bb[i] = *reinterpret_cast<const bf16x8*>(Bs + (wc * 64 + i * 16 + lo) * 32 + ru);
    #pragma unroll
    for (int mi = 0; mi < 4; ++mi)
      #pragma unroll
      for (int ni = 0; ni < 4; ++ni)
        acc[mi][ni] = mfma16(af[mi], bb[ni], acc[mi][ni]);
    __syncthreads();
  }
  #pragma unroll
  for (int mi = 0; mi < 4; ++mi)
    #pragma unroll
    for (int ni = 0; ni < 4; ++ni)
      #pragma unroll
      for (int r = 0; r < 4; ++r) {
        const size_t row = m0 + wr * 64 + mi * 16 + hi * 4 + r;
        const size_t col = n0 + wc * 64 + ni * 16 + lo;
        Cf[row * N + col] = acc[mi][ni][r];
      }
}

// ---------------- causal flash attention fwd (v3) ----------------
// 512 thr / 8 waves, q-tile 128 rows (16/wave), KVBLK=64, grid (8,16,2)=256
// blocks (1/CU). Balanced passes (i, 15-i) -> uniform 34 KV-tiles/block.
// Same swapped-QK^T / in-lane softmax / packed-P math as v2.
__global__ __launch_bounds__(512) void flash_fwd(
    const bf16* __restrict__ Qg, const bf16* __restrict__ Kg,
    const bf16* __restrict__ Vg, bf16* __restrict__ Og) {
  const int t = threadIdx.x;
  const int wid = t >> 6, lane = t & 63, lo = lane & 15, hi = lane >> 4;
  const int h  = blockIdx.y;
  const int b  = blockIdx.z;

  __shared__ bf16 Ks[64 * 128];    // [kv][d]  swizzled (16 units/row, key kv&15)
  __shared__ bf16 Vt[128 * 64];    // [d][kv]  swizzled (key (d^(d>>3))&7)
  __shared__ bf16 Ps[8][16 * 64];  // per-wave P [q][kv], 16B-unit swizzle key q&7

  const size_t hoff = (size_t)b * SEQL * DM + (size_t)h * HD;
  const float SCALE_LOG2 = 0.12751743f;   // (1/sqrt(128)) * log2(e)

  const int krow = t >> 4;                  // 0..31
  const int kul  = ((t & 15) ^ (krow & 15)) * 8;
  const int vd0  = (t & 31) * 4;            // 4 d-cols per thread
  const int vg   = (t >> 5) & 15;           // kv-group 0..15 (4 rows each)
  char* myP = (char*)(Ps[wid]);
  const f32x4 zero4 = {0.f, 0.f, 0.f, 0.f};

  #pragma unroll 1
  for (int pass = 0; pass < 2; ++pass) {
    const int q0 = (pass ? (15 - (int)blockIdx.x) : (int)blockIdx.x) * 128;

    // Q B-frags: q = q0 + wid*16 + lo, k-chunk kc*32 + hi*8
    bf16x8 qf[4];
    {
      const bf16* qrow = Qg + hoff + (size_t)(q0 + wid * 16 + lo) * DM;
      #pragma unroll
      for (int kc = 0; kc < 4; ++kc)
        qf[kc] = *reinterpret_cast<const bf16x8*>(qrow + kc * 32 + hi * 8);
    }

    f32x4 acc[8];
    #pragma unroll
    for (int i = 0; i < 8; ++i) acc[i] = zero4;
    float m_run = -1e30f, l_run = 0.f;

    const int ntiles = q0 / 64 + 2;
    #pragma unroll 1
    for (int it = 0; it < ntiles; ++it) {
      const int kv0 = it * 64;
      // ---- stage K tile (2 x global_load_lds, pre-swizzled source) ----
      {
        const bf16* gK = Kg + hoff + (size_t)(kv0 + krow) * DM + kul;
        char* lK = (char*)Ks + wid * 1024;
        gload16(gK, lK);
        gload16(gK + (size_t)32 * DM, lK + 8192);
      }
      // ---- stage V^T tile (coalesced 8B loads -> swizzled b64 writes) ----
      {
        const bf16* gV = Vg + hoff + (size_t)(kv0 + vg * 4) * DM + vd0;
        bf16x4 ld[4];
        #pragma unroll
        for (int e = 0; e < 4; ++e)
          ld[e] = *reinterpret_cast<const bf16x4*>(gV + (size_t)e * DM);
        #pragma unroll
        for (int c = 0; c < 4; ++c) {
          const int d = vd0 + c;
          const int sw = (d ^ (d >> 3)) & 7;
          bf16x4 w;
          #pragma unroll
          for (int e = 0; e < 4; ++e) w[e] = ld[e][c];
          *reinterpret_cast<bf16x4*>(Vt + d * 64 + (((vg >> 1) ^ sw) * 8) +
                                     (vg & 1) * 4) = w;
        }
      }
      __syncthreads();

      // ---- S^T = K Q^T: lane holds s for q=q0+wid*16+lo,
      //      kv = kv0 + nf*16 + hi*4 + r ----
      f32x4 s[4];
      #pragma unroll
      for (int nf = 0; nf < 4; ++nf) s[nf] = zero4;
      #pragma unroll
      for (int nf = 0; nf < 4; ++nf) {
        const bf16* krp = Ks + (nf * 16 + lo) * 128;
        #pragma unroll
        for (int kc = 0; kc < 4; ++kc) {
          const bf16x8 kb = *reinterpret_cast<const bf16x8*>(krp + (((kc * 4 + hi) ^ lo) * 8));
          s[nf] = mfma16(kb, qf[kc], s[nf]);
        }
      }
      // ---- scale(+log2e) + causal mask ----
      const bool boundary = (kv0 + 63 > q0 + wid * 16);
      #pragma unroll
      for (int nf = 0; nf < 4; ++nf)
        #pragma unroll
        for (int r = 0; r < 4; ++r) {
          float v = s[nf][r] * SCALE_LOG2;
          if (boundary && (kv0 + nf * 16 + hi * 4 + r > q0 + wid * 16 + lo)) v = -1e30f;
          s[nf][r] = v;
        }
      // ---- in-lane online softmax ----
      float pmax = -1e30f;
      #pragma unroll
      for (int nf = 0; nf < 4; ++nf)
        #pragma unroll
        for (int r = 0; r < 4; ++r) pmax = fmaxf(pmax, s[nf][r]);
      pmax = fmaxf(pmax, __shfl_xor(pmax, 16, 64));
      pmax = fmaxf(pmax, __shfl_xor(pmax, 32, 64));
      float mnew = m_run;
      if (!__all(pmax <= m_run)) {
        mnew = fmaxf(m_run, pmax);
        const float fctr = exp2f(m_run - mnew);
        m_run = mnew;
        l_run *= fctr;
        float fa[4];
        #pragma unroll
        for (int r = 0; r < 4; ++r) fa[r] = __shfl(fctr, hi * 4 + r, 64);
        #pragma unroll
        for (int i = 0; i < 8; ++i)
          #pragma unroll
          for (int r = 0; r < 4; ++r) acc[i][r] *= fa[r];
      }
      float sum = 0.f;
      #pragma unroll
      for (int nf = 0; nf < 4; ++nf)
        #pragma unroll
        for (int r = 0; r < 4; ++r) {
          const float p = exp2f(s[nf][r] - mnew);
          s[nf][r] = p;
          sum += p;
        }
      sum += __shfl_xor(sum, 16, 64);
      sum += __shfl_xor(sum, 32, 64);
      l_run += sum;
      // ---- P -> LDS (packed b64, 16B-unit swizzle key q&7) ----
      #pragma unroll
      for (int nf = 0; nf < 4; ++nf) {
        bf16x4 w;
        #pragma unroll
        for (int r = 0; r < 4; ++r) w[r] = (bf16)s[nf][r];
        *reinterpret_cast<bf16x4*>(myP + lo * 128 +
            (((nf * 2 + (hi >> 1)) ^ (lo & 7)) * 16) + (hi & 1) * 8) = w;
      }
      // ---- P A-frags ----
      bf16x8 pa[2];
      #pragma unroll
      for (int kc = 0; kc < 2; ++kc)
        pa[kc] = *reinterpret_cast<const bf16x8*>(myP + lo * 128 +
            (((kc * 4 + hi) ^ (lo & 7)) * 16));
      // ---- O += P V ----
      #pragma unroll
      for (int nf = 0; nf < 8; ++nf) {
        const int d = nf * 16 + lo;
        const int sw = (d ^ (d >> 3)) & 7;
        const bf16* vrp = Vt + d * 64;
        #pragma unroll
        for (int kc = 0; kc < 2; ++kc) {
          const bf16x8 bv = *reinterpret_cast<const bf16x8*>(vrp + (((kc * 4 + hi) ^ sw) * 8));
          acc[nf] = mfma16(pa[kc], bv, acc[nf]);
        }
      }
      __syncthreads();
    }

    // ---- finalize ----
    const float linv = 1.f / l_run;
    float la[4];
    #pragma unroll
    for (int r = 0; r < 4; ++r) la[r] = __shfl(linv, hi * 4 + r, 64);
    #pragma unroll
    for (int nf = 0; nf < 8; ++nf)
      #pragma unroll
      for (int r = 0; r < 4; ++r) {
        const size_t row = q0 + wid * 16 + hi * 4 + r;
        Og[hoff + row * DM + nf * 16 + lo] = (bf16)(acc[nf][r] * la[r]);
      }
  }
}

extern "C" void kernel_launch(void* const* d_in, const int* in_sizes, int n_in,
                              void* d_out, int out_size, void* d_ws, size_t ws_size,
                              hipStream_t stream) {
  const float* x  = (const float*)d_in[0];
  const float* wq = (const float*)d_in[1];
  const float* wk = (const float*)d_in[2];
  const float* wv = (const float*)d_in[3];
  const float* wo = (const float*)d_in[4];
  const float* fc = (const float*)d_in[5];
  const float* fs = (const float*)d_in[6];
  float* out = (float*)d_out;

  char* ws = (char*)d_ws;
  bf16* xb    = (bf16*)ws;                      // 16MB  x bf16; reused as O
  bf16* wqkvt = (bf16*)(ws + (16ull << 20));    // 24MB
  bf16* wot   = (bf16*)(ws + (40ull << 20));    //  8MB
  bf16* qkv   = (bf16*)(ws + (48ull << 20));    // 48MB
  bf16* Qb = qkv;
  bf16* Kb = qkv + (size_t)MR * DM;
  bf16* Vb = qkv + 2 * (size_t)MR * DM;

  cvt_x<<<8192, 256, 0, stream>>>(x, xb);
  transpose_w<<<dim3(64, 64, 4), dim3(32, 8), 0, stream>>>(wq, wk, wv, wo, wqkvt, wot);
  gemm8<<<384, 512, 0, stream>>>(xb, wqkvt, qkv, MR, DM, DM);
  rope_k<<<dim3(4096, 2), 256, 0, stream>>>(Qb, Kb, fc, fs);
  flash_fwd<<<dim3(8, 16, 2), 512, 0, stream>>>(Qb, Kb, Vb, xb /*O*/);
  gemm_bt_f32<<<dim3(16, 32), 256, 0, stream>>>(xb, wot, out, MR, DM, DM);
}